// Round 4
// baseline (4574.702 us; speedup 1.0000x reference)
//
#include <hip/hip_runtime.h>

#define N_USERS 100000
#define N_ITEMS 50000
#define N_NODES 150000
#define EMBED   64
#define NNZV    4000000
#define BATCH   4096

// ---- col-blocked bucket layout ---------------------------------------------
// bucket = row >> 7  : 128 rows/bucket, 1172 buckets; acc = 32 KB -> 5 blk/CU
// colblk = col >> 13 : 8192 cols/blk = 2 MB embeddings -> fits 4 MB XCD L2
// segment = bucket*19 + colblk : edges sorted bucket-major, colblk-minor.
// R2 measured FETCH=385MB for bspmm -> the L2-locality mechanism is PROVEN.
// R2's 1430us/bspmm was the serial inner loop + generic-ptr atomic (flat CAS);
// fixed here with quarter-wave edges + true __shared__ ds_add_f32.
// Workspace stays at the R2-proven ~109 MB envelope (staging overlays E_a/E_b,
// dense edges rebuilt by k_compact) — round-3's 122 MB persistent-staging
// layout is the prime suspect for the container crash.
#define BROWS   128
#define NBKT    1172               // ceil(150000/128)
#define NCB     19                 // ceil(150000/8192)
#define NSEG    (NBKT * NCB)       // 22268 (even)
#define CAP2    320                // staging cap/segment: mean 186, ~9.8 sigma
#define EPB     8192               // edges per k_part block

// ---------------- Phase A: partition edges into segments ---------------------
// (verbatim from the round-2 kernel that PASSED correctness)
// Packed u16 LDS counters double as count (pass 1) then global-base+rank
// cursor (pass 2). Plain (non-nt) staging stores: scattered 8B writes need
// L2 write-merge (R11 lesson). Record: low32 = (r&127)<<18 | col, hi32 = val.
__global__ __launch_bounds__(512) void k_part(
        const int* __restrict__ row, const int* __restrict__ col,
        const float* __restrict__ vals, int* __restrict__ gcnt,
        unsigned long long* __restrict__ staging) {
    __shared__ unsigned int cntp[NSEG / 2];          // 44.5 KB
    int tid = threadIdx.x;
    for (int i = tid; i < NSEG / 2; i += 512) cntp[i] = 0u;
    __syncthreads();
    int e0 = blockIdx.x * EPB;
    int er[16], ec[16];
    #pragma unroll
    for (int k = 0; k < 16; k++) {
        int e = e0 + k * 512 + tid;
        er[k] = 0; ec[k] = 0;
        if (e < NNZV) {
            er[k] = row[e];
            ec[k] = col[e];
            int s = (er[k] >> 7) * NCB + (ec[k] >> 13);
            atomicAdd(&cntp[s >> 1], 1u << ((s & 1) * 16));
        }
    }
    __syncthreads();
    // reserve global ranges; overwrite packed counts with packed global bases
    for (int w = tid; w < NSEG / 2; w += 512) {
        unsigned int pc = cntp[w];
        unsigned int c0 = pc & 0xffffu, c1 = pc >> 16;
        unsigned int g0 = c0 ? (unsigned int)atomicAdd(&gcnt[2 * w], (int)c0) : 0u;
        unsigned int g1 = c1 ? (unsigned int)atomicAdd(&gcnt[2 * w + 1], (int)c1) : 0u;
        cntp[w] = g0 | (g1 << 16);
    }
    __syncthreads();
    #pragma unroll
    for (int k = 0; k < 16; k++) {
        int e = e0 + k * 512 + tid;
        if (e < NNZV) {
            int r = er[k], c = ec[k];
            int s = (r >> 7) * NCB + (c >> 13);
            unsigned int old = atomicAdd(&cntp[s >> 1], 1u << ((s & 1) * 16));
            unsigned int idx = (old >> ((s & 1) * 16)) & 0xffffu;   // base+rank
            unsigned long long rec = ((unsigned long long)__float_as_uint(vals[e]) << 32)
                                   | ((unsigned int)(r & (BROWS - 1)) << 18)
                                   | (unsigned int)c;
            staging[(size_t)s * CAP2 + idx] = rec;
        }
    }
}

// ---------------- exclusive scan of segment counts (R2-verbatim) -------------
#define SCAN_T 1024
#define SCAN_C 22          // 1024*22 = 22528 >= NSEG
__global__ __launch_bounds__(SCAN_T) void k_scan(const int* __restrict__ gcnt,
                                                 int* __restrict__ seg_ptr) {
    __shared__ int sh[SCAN_T];
    int t = threadIdx.x;
    int loc[SCAN_C];
    int s = 0;
    #pragma unroll
    for (int i = 0; i < SCAN_C; i++) {
        int idx = t * SCAN_C + i;
        loc[i] = s;
        s += (idx < NSEG) ? gcnt[idx] : 0;
    }
    sh[t] = s;
    __syncthreads();
    for (int off = 1; off < SCAN_T; off <<= 1) {
        int u = (t >= off) ? sh[t - off] : 0;
        __syncthreads();
        sh[t] += u;
        __syncthreads();
    }
    int excl = sh[t] - s;
    #pragma unroll
    for (int i = 0; i < SCAN_C; i++) {
        int idx = t * SCAN_C + i;
        if (idx < NSEG) seg_ptr[idx] = excl + loc[i];
    }
    if (t == SCAN_T - 1) seg_ptr[NSEG] = sh[t];
}

// ---------------- compact padded staging -> dense edges (R2-verbatim) --------
__global__ __launch_bounds__(256) void k_compact(const int* __restrict__ seg_ptr,
        const unsigned long long* __restrict__ staging,
        unsigned long long* __restrict__ edges) {
    for (int s = blockIdx.x; s < NSEG; s += gridDim.x) {
        int st = seg_ptr[s], en = seg_ptr[s + 1];
        const unsigned long long* src = staging + (size_t)s * CAP2;
        for (int i = threadIdx.x; i < en - st; i += 256)
            edges[st + i] = src[i];
    }
}

// ---------------- col-blocked SpMM (quarter-wave per edge) -------------------
// 256 thr own one 128-row bucket; its edges are one contiguous dense span
// [seg_ptr[b*19], seg_ptr[b*19+19]) in colblk order (locality preserved).
// Per wave: 4 edges in flight (g = lane>>4 edge slot, d = lane&15 float4 dim)
// — the R0-proven decomposition. Accumulate with atomicAdd on TRUE
// __shared__ float -> hardware ds_add_f32 (no generic-ptr CAS, the R2 killer).
// Rotate-by-rl column swizzle: addr = rl*64 + ((4d+j+rl)&63) -> within a
// 16-lane group 8 banks x 2-way (free, m136); random rl decorrelates the 4
// groups. Output pass unswizzles once. Tail overshoot lanes hold rec=0
// (cc=0, vv=0): gather row 0, atomicAdd(0) -> harmless; kmax wave-uniform.
__global__ __launch_bounds__(256) void k_bspmm(
        const int* __restrict__ seg_ptr,
        const unsigned long long* __restrict__ edges,
        const float4* __restrict__ Eu4,    // base for cc <  N_USERS
        const float4* __restrict__ Ei4s,   // pre-shifted base for cc >= N_USERS
        float4* __restrict__ Eout4) {
    __shared__ float acc[BROWS * EMBED];   // 32 KB -> 5 blocks/CU
    int b = blockIdx.x;
    for (int i = threadIdx.x; i < BROWS * EMBED / 4; i += 256)
        ((float4*)acc)[i] = make_float4(0.f, 0.f, 0.f, 0.f);
    __syncthreads();
    int lane = threadIdx.x & 63;
    int w    = threadIdx.x >> 6;
    int g    = lane >> 4;
    int d    = lane & 15;
    int st = seg_ptr[b * NCB];
    int en = seg_ptr[b * NCB + NCB];
    for (int c0 = st + w * 64; c0 < en; c0 += 256) {
        int m = en - c0; if (m > 64) m = 64;
        unsigned long long rec = 0ull;
        if (lane < m) rec = __builtin_nontemporal_load(edges + c0 + lane);
        int clo = (int)(unsigned int)rec;
        int vhi = (int)(rec >> 32);
        int kmax = (m + 3) >> 2;           // wave-uniform trip count
        #pragma unroll 4
        for (int k = 0; k < kmax; k++) {
            int src = 4 * k + g;
            int kk  = __shfl(clo, src);
            float vv = __int_as_float(__shfl(vhi, src));
            int cc = kk & 0x3FFFF;
            int rl = kk >> 18;
            const float4* bp = (cc < N_USERS) ? Eu4 : Ei4s;
            float4 e = bp[(size_t)cc * 16 + d];
            int rb = rl << 6;
            int c4 = (d << 2) + rl;
            atomicAdd(&acc[rb + ((c4 + 0) & 63)], vv * e.x);
            atomicAdd(&acc[rb + ((c4 + 1) & 63)], vv * e.y);
            atomicAdd(&acc[rb + ((c4 + 2) & 63)], vv * e.z);
            atomicAdd(&acc[rb + ((c4 + 3) & 63)], vv * e.w);
        }
    }
    __syncthreads();
    size_t r0 = (size_t)b * BROWS;
    for (int i = threadIdx.x; i < BROWS * 16; i += 256) {
        int rl = i >> 4;
        int q  = i & 15;
        size_t rr = r0 + (size_t)rl;
        if (rr < N_NODES) {
            int c = q << 2;
            float4 o;
            o.x = acc[(rl << 6) + ((c + 0 + rl) & 63)];
            o.y = acc[(rl << 6) + ((c + 1 + rl) & 63)];
            o.z = acc[(rl << 6) + ((c + 2 + rl) & 63)];
            o.w = acc[(rl << 6) + ((c + 3 + rl) & 63)];
            Eout4[rr * 16 + q] = o;
        }
    }
}

// ---------------- init gather: out = 0.25 * E0[batch] (virtual concat) -------
__global__ void k_gather_init(const int* __restrict__ bu, const int* __restrict__ bp,
                              const int* __restrict__ bn,
                              const float4* __restrict__ eu4,
                              const float4* __restrict__ ei4s,
                              float4* __restrict__ out) {
    int idx = blockIdx.x * blockDim.x + threadIdx.x;
    if (idx >= 3 * BATCH * 16) return;
    int j = idx >> 4;
    int d = idx & 15;
    int node;
    if (j < BATCH)          node = bu[j];
    else if (j < 2 * BATCH) node = N_USERS + bp[j - BATCH];
    else                    node = N_USERS + bn[j - 2 * BATCH];
    const float4* basep = (node < N_USERS) ? eu4 : ei4s;
    float4 v = basep[node * 16 + d];
    v.x *= 0.25f; v.y *= 0.25f; v.z *= 0.25f; v.w *= 0.25f;
    out[idx] = v;
}

// ---------------- accumulate gather: out += 0.25 * E[batch] ------------------
__global__ void k_gather_acc(const int* __restrict__ bu, const int* __restrict__ bp,
                             const int* __restrict__ bn, const float4* __restrict__ E,
                             float4* __restrict__ out) {
    int idx = blockIdx.x * blockDim.x + threadIdx.x;
    if (idx >= 3 * BATCH * 16) return;
    int j = idx >> 4;
    int d = idx & 15;
    int node;
    if (j < BATCH)          node = bu[j];
    else if (j < 2 * BATCH) node = N_USERS + bp[j - BATCH];
    else                    node = N_USERS + bn[j - 2 * BATCH];
    float4 v = E[node * 16 + d];
    float4 o = out[idx];
    o.x += 0.25f * v.x; o.y += 0.25f * v.y; o.z += 0.25f * v.z; o.w += 0.25f * v.w;
    out[idx] = o;
}

extern "C" void kernel_launch(void* const* d_in, const int* in_sizes, int n_in,
                              void* d_out, int out_size, void* d_ws, size_t ws_size,
                              hipStream_t stream) {
    const int*   bu   = (const int*)d_in[0];
    const int*   bp   = (const int*)d_in[1];
    const int*   bn   = (const int*)d_in[2];
    const float* eu   = (const float*)d_in[3];
    const float* ei   = (const float*)d_in[4];
    const int*   row  = (const int*)d_in[5];
    const int*   col  = (const int*)d_in[6];
    const float* vals = (const float*)d_in[7];
    float* out = (float*)d_out;

    char* p = (char*)d_ws;
    auto alloc = [&](size_t nbytes) {
        void* r = (void*)p;
        p += (nbytes + 255) & ~(size_t)255;
        return r;
    };
    float*              E_a     = (float*)alloc((size_t)N_NODES * EMBED * 4);  // 38.4 MB
    float*              E_b     = (float*)alloc((size_t)N_NODES * EMBED * 4);  // 38.4 MB
    unsigned long long* edges   = (unsigned long long*)alloc((size_t)NNZV * 8);// 32.0 MB
    int*                seg_ptr = (int*)alloc((size_t)(NSEG + 1) * 4);
    int*                gcnt    = (int*)alloc((size_t)NSEG * 4);
    (void)ws_size; (void)n_in; (void)in_sizes; (void)out_size;

    // staging (NSEG*CAP2*8 = 57.0 MB) overlays E_a+E_b (76.8 MB): dead after
    // k_compact, before layer-1 bspmm writes E_a (same stream => ordered).
    // Total footprint ~109 MB = the R2-proven envelope.
    unsigned long long* staging = (unsigned long long*)E_a;

    const float4* eu4  = (const float4*)eu;
    const float4* ei4s = (const float4*)ei - (size_t)N_USERS * 16;  // pre-shifted

    hipMemsetAsync(gcnt, 0, (size_t)NSEG * 4, stream);

    k_part<<<(NNZV + EPB - 1) / EPB, 512, 0, stream>>>(row, col, vals, gcnt, staging);
    k_scan<<<1, SCAN_T, 0, stream>>>(gcnt, seg_ptr);
    k_compact<<<2048, 256, 0, stream>>>(seg_ptr, staging, edges);

    // out = 0.25 * E0[batch]
    k_gather_init<<<(3 * BATCH * 16 + 255) / 256, 256, 0, stream>>>(
        bu, bp, bn, eu4, ei4s, (float4*)out);

    // layer 1: E1 = A * E0 (virtual concat input)
    k_bspmm<<<NBKT, 256, 0, stream>>>(seg_ptr, edges, eu4, ei4s, (float4*)E_a);
    k_gather_acc<<<(3 * BATCH * 16 + 255) / 256, 256, 0, stream>>>(
        bu, bp, bn, (const float4*)E_a, (float4*)out);

    // layer 2: E2 = A * E1 (global node ids -> both bases = E_a, no shift)
    k_bspmm<<<NBKT, 256, 0, stream>>>(seg_ptr, edges, (const float4*)E_a,
                                      (const float4*)E_a, (float4*)E_b);
    k_gather_acc<<<(3 * BATCH * 16 + 255) / 256, 256, 0, stream>>>(
        bu, bp, bn, (const float4*)E_b, (float4*)out);

    // layer 3: E3 = A * E2
    k_bspmm<<<NBKT, 256, 0, stream>>>(seg_ptr, edges, (const float4*)E_b,
                                      (const float4*)E_b, (float4*)E_a);
    k_gather_acc<<<(3 * BATCH * 16 + 255) / 256, 256, 0, stream>>>(
        bu, bp, bn, (const float4*)E_a, (float4*)out);
}

// Round 5
// 1963.212 us; speedup vs baseline: 2.3302x; 2.3302x over previous
//
#include <hip/hip_runtime.h>

#define N_USERS 100000
#define N_ITEMS 50000
#define N_NODES 150000
#define EMBED   64
#define NNZV    4000000
#define BATCH   4096

// ---- col-blocked + row-class layout ----------------------------------------
// bucket = row >> 7 (128 rows, 1172); colblk = col >> 13 (8192 cols, 2 MB);
// class = (row >> 5) & 3  (which 32-row quarter of the bucket).
// fine key = (bucket*19 + colblk)*4 + class  -> 89,072 keys.
// In k_bspmm, wave w consumes ONLY class-w edges and owns rows 32w..32w+31 of
// the block's LDS accumulator -> non-atomic ds_read/fmac/ds_write RMW.
// WHY: R2 & R4 both measured ~1440us/bspmm with ~1 wave-level ds_add_f32 per
// edge; 1446us*2.4GHz*256CU / 256M lane-atomics = 3.4 cyc/lane -> wave64 LDS
// f32 atomics serialize per-lane (~220 cyc/instr). Ownership removes them.
#define BROWS   128
#define NBKT    1172                 // ceil(150000/128)
#define NCB     19                   // ceil(150000/8192)
#define NCLS    4
#define NSEGF   (NBKT * NCB * NCLS)  // 89072
#define CAP3    88                   // mean 44.9, sd 6.7 -> P(overflow) ~ 1e-3 overall
#define EPB     8192                 // edges per k_part block

// ---------------- Phase A: partition edges into padded fine segments ---------
// 3-phase structure proven in R2/R4; counters now u8 x4 packed (87 KB LDS,
// 1 block/CU). Cell holds count (phase 1) then global-base+rank cursor
// (phases 2-3); base+rank <= CAP3=88 < 256 so u8 is safe. Plain (non-nt)
// staging stores: scattered 8B writes need L2 write-merge (R11 lesson).
// Record: low32 = (r&127)<<18 | col, high32 = val bits.
__global__ __launch_bounds__(512) void k_part(
        const int* __restrict__ row, const int* __restrict__ col,
        const float* __restrict__ vals, int* __restrict__ gcnt,
        unsigned long long* __restrict__ staging) {
    __shared__ unsigned int cntp[NSEGF / 4];         // 22268 u32 = 87 KB
    int tid = threadIdx.x;
    for (int i = tid; i < NSEGF / 4; i += 512) cntp[i] = 0u;
    __syncthreads();
    int e0 = blockIdx.x * EPB;
    int er[16], ec[16];
    #pragma unroll
    for (int k = 0; k < 16; k++) {
        int e = e0 + k * 512 + tid;
        er[k] = 0; ec[k] = 0;
        if (e < NNZV) {
            int r = row[e], c = col[e];
            er[k] = r; ec[k] = c;
            int fk = ((r >> 7) * NCB + (c >> 13)) * NCLS + ((r >> 5) & 3);
            atomicAdd(&cntp[fk >> 2], 1u << ((fk & 3) * 8));
        }
    }
    __syncthreads();
    // reserve global ranges per key; replace packed counts with packed bases
    for (int w = tid; w < NSEGF / 4; w += 512) {
        unsigned int pc = cntp[w];
        if (!pc) continue;
        unsigned int nb = 0u;
        #pragma unroll
        for (int j = 0; j < 4; j++) {
            unsigned int cj = (pc >> (j * 8)) & 0xffu;
            if (cj) {
                unsigned int gj = (unsigned int)atomicAdd(&gcnt[4 * w + j], (int)cj);
                nb |= gj << (j * 8);
            }
        }
        cntp[w] = nb;
    }
    __syncthreads();
    #pragma unroll
    for (int k = 0; k < 16; k++) {
        int e = e0 + k * 512 + tid;
        if (e < NNZV) {
            int r = er[k], c = ec[k];
            int fk = ((r >> 7) * NCB + (c >> 13)) * NCLS + ((r >> 5) & 3);
            unsigned int sh = (fk & 3) * 8;
            unsigned int old = atomicAdd(&cntp[fk >> 2], 1u << sh);
            unsigned int idx = (old >> sh) & 0xffu;           // base + rank
            unsigned long long rec = ((unsigned long long)__float_as_uint(vals[e]) << 32)
                                   | ((unsigned int)(r & (BROWS - 1)) << 18)
                                   | (unsigned int)c;
            staging[(size_t)fk * CAP3 + idx] = rec;
        }
    }
}

// ---------------- 3-kernel exclusive scan over 89,072 counts -----------------
#define SCB 348          // ceil(NSEGF/256)
__global__ __launch_bounds__(256) void k_scanA(const int* __restrict__ gcnt,
                                               int* __restrict__ bsum) {
    __shared__ int sh[256];
    int t = threadIdx.x;
    int i = blockIdx.x * 256 + t;
    sh[t] = (i < NSEGF) ? gcnt[i] : 0;
    __syncthreads();
    for (int off = 128; off > 0; off >>= 1) {
        if (t < off) sh[t] += sh[t + off];
        __syncthreads();
    }
    if (t == 0) bsum[blockIdx.x] = sh[0];
}
__global__ __launch_bounds__(512) void k_scanB(int* __restrict__ bsum) {
    __shared__ int sh[512];
    int t = threadIdx.x;
    int v = (t < SCB) ? bsum[t] : 0;
    sh[t] = v;
    __syncthreads();
    for (int off = 1; off < 512; off <<= 1) {
        int u = (t >= off) ? sh[t - off] : 0;
        __syncthreads();
        sh[t] += u;
        __syncthreads();
    }
    if (t < SCB) bsum[t] = sh[t] - v;     // exclusive
}
__global__ __launch_bounds__(256) void k_scanC(const int* __restrict__ gcnt,
                                               const int* __restrict__ bsum,
                                               int* __restrict__ seg_ptr) {
    __shared__ int sh[256];
    int t = threadIdx.x;
    int i = blockIdx.x * 256 + t;
    int v = (i < NSEGF) ? gcnt[i] : 0;
    sh[t] = v;
    __syncthreads();
    for (int off = 1; off < 256; off <<= 1) {
        int u = (t >= off) ? sh[t - off] : 0;
        __syncthreads();
        sh[t] += u;
        __syncthreads();
    }
    int base = bsum[blockIdx.x];
    if (i < NSEGF) seg_ptr[i] = base + sh[t] - v;
    if (i == NSEGF - 1) seg_ptr[NSEGF] = base + sh[t];
}

// ---------------- compact padded staging -> dense edges ----------------------
__global__ __launch_bounds__(256) void k_compact(const int* __restrict__ seg_ptr,
        const unsigned long long* __restrict__ staging,
        unsigned long long* __restrict__ edges) {
    for (int s = blockIdx.x; s < NSEGF; s += gridDim.x) {
        int st = seg_ptr[s], en = seg_ptr[s + 1];
        const unsigned long long* src = staging + (size_t)s * CAP3;
        for (int i = threadIdx.x; i < en - st; i += 256)
            edges[st + i] = src[i];
    }
}

// ---------------- col-blocked SpMM, ownership-partitioned, ATOMIC-FREE -------
// Block = 256 thr = one 128-row bucket; acc[128][64] f32 in LDS (32 KB ->
// 5 blk/CU = 20 waves). Wave w sweeps its 19 class-w spans in colblk order
// (gathers stay in a 2 MB L2 window; FETCH floor proven at ~390 MB in R2/R4).
// One edge per wave-step: readlane -> SGPR broadcast (cc,rl,vv), scalar base
// select, gather E[cc*64+lane] (256B coalesced), RMW acc[rl*64+lane] via
// plain read+fmac+write: addresses = banks 0..31 x2 lanes -> conflict-free;
// same-wave DS ops are in-order so back-to-back same-row edges are safe.
// No atomics. No barriers (waves own disjoint acc slices and output rows).
__global__ __launch_bounds__(256) void k_bspmm(
        const int* __restrict__ seg_ptr,
        const unsigned long long* __restrict__ edges,
        const float* __restrict__ Eu,      // base for cc <  N_USERS
        const float* __restrict__ Ei_s,    // pre-shifted base for cc >= N_USERS
        float4* __restrict__ Eout4) {
    __shared__ float4 accv[BROWS * 16];    // 32 KB
    float* acc = (float*)accv;
    int b    = blockIdx.x;
    int w    = threadIdx.x >> 6;
    int lane = threadIdx.x & 63;
    // init own slice (rows 32w..32w+31), wave-private -> no sync
    #pragma unroll
    for (int j = 0; j < 8; j++)
        accv[w * 512 + j * 64 + lane] = make_float4(0.f, 0.f, 0.f, 0.f);
    for (int cb = 0; cb < NCB; cb++) {
        int fk = (b * NCB + cb) * NCLS + w;
        int st = seg_ptr[fk];
        int en = seg_ptr[fk + 1];
        for (int c0 = st; c0 < en; c0 += 64) {
            int m = en - c0; if (m > 64) m = 64;
            unsigned long long rec = 0ull;
            if (lane < m) rec = edges[c0 + lane];
            int clo = (int)(unsigned int)rec;
            int vhi = (int)(rec >> 32);
            #pragma unroll 4
            for (int k = 0; k < m; k++) {
                int kk   = __builtin_amdgcn_readlane(clo, k);
                float vv = __int_as_float(__builtin_amdgcn_readlane(vhi, k));
                int cc = kk & 0x3FFFF;
                int rl = kk >> 18;
                const float* ep = (cc < N_USERS) ? Eu : Ei_s;   // scalar select
                float ev = ep[cc * 64 + lane];                  // 256B coalesced
                int a = (rl << 6) + lane;                       // conflict-free
                acc[a] += vv * ev;                              // ds r/fmac/w
            }
        }
    }
    // writeout own rows (no sync needed)
    size_t r0 = (size_t)b * BROWS + w * 32;
    #pragma unroll
    for (int i = 0; i < 8; i++) {
        int idx = i * 64 + lane;
        int rr  = idx >> 4;
        int q   = idx & 15;
        size_t R = r0 + (size_t)rr;
        if (R < N_NODES) Eout4[R * 16 + q] = accv[(w * 32 + rr) * 16 + q];
    }
}

// ---------------- init gather: out = 0.25 * E0[batch] (virtual concat) -------
__global__ void k_gather_init(const int* __restrict__ bu, const int* __restrict__ bp,
                              const int* __restrict__ bn,
                              const float4* __restrict__ eu4,
                              const float4* __restrict__ ei4s,
                              float4* __restrict__ out) {
    int idx = blockIdx.x * blockDim.x + threadIdx.x;
    if (idx >= 3 * BATCH * 16) return;
    int j = idx >> 4;
    int d = idx & 15;
    int node;
    if (j < BATCH)          node = bu[j];
    else if (j < 2 * BATCH) node = N_USERS + bp[j - BATCH];
    else                    node = N_USERS + bn[j - 2 * BATCH];
    const float4* basep = (node < N_USERS) ? eu4 : ei4s;
    float4 v = basep[node * 16 + d];
    v.x *= 0.25f; v.y *= 0.25f; v.z *= 0.25f; v.w *= 0.25f;
    out[idx] = v;
}

// ---------------- accumulate gather: out += 0.25 * E[batch] ------------------
__global__ void k_gather_acc(const int* __restrict__ bu, const int* __restrict__ bp,
                             const int* __restrict__ bn, const float4* __restrict__ E,
                             float4* __restrict__ out) {
    int idx = blockIdx.x * blockDim.x + threadIdx.x;
    if (idx >= 3 * BATCH * 16) return;
    int j = idx >> 4;
    int d = idx & 15;
    int node;
    if (j < BATCH)          node = bu[j];
    else if (j < 2 * BATCH) node = N_USERS + bp[j - BATCH];
    else                    node = N_USERS + bn[j - 2 * BATCH];
    float4 v = E[node * 16 + d];
    float4 o = out[idx];
    o.x += 0.25f * v.x; o.y += 0.25f * v.y; o.z += 0.25f * v.z; o.w += 0.25f * v.w;
    out[idx] = o;
}

extern "C" void kernel_launch(void* const* d_in, const int* in_sizes, int n_in,
                              void* d_out, int out_size, void* d_ws, size_t ws_size,
                              hipStream_t stream) {
    const int*   bu   = (const int*)d_in[0];
    const int*   bp   = (const int*)d_in[1];
    const int*   bn   = (const int*)d_in[2];
    const float* eu   = (const float*)d_in[3];
    const float* ei   = (const float*)d_in[4];
    const int*   row  = (const int*)d_in[5];
    const int*   col  = (const int*)d_in[6];
    const float* vals = (const float*)d_in[7];
    float* out = (float*)d_out;

    char* p = (char*)d_ws;
    auto alloc = [&](size_t nbytes) {
        void* r = (void*)p;
        p += (nbytes + 255) & ~(size_t)255;
        return r;
    };
    float*              E_a     = (float*)alloc((size_t)N_NODES * EMBED * 4);  // 38.4 MB
    float*              E_b     = (float*)alloc((size_t)N_NODES * EMBED * 4);  // 38.4 MB
    unsigned long long* edges   = (unsigned long long*)alloc((size_t)NNZV * 8);// 32.0 MB
    int*                seg_ptr = (int*)alloc((size_t)(NSEGF + 1) * 4);        // 356 KB
    int*                gcnt    = (int*)alloc((size_t)NSEGF * 4);              // 356 KB
    int*                bsum    = (int*)alloc((size_t)SCB * 4);
    (void)ws_size; (void)n_in; (void)in_sizes; (void)out_size;

    // staging (NSEGF*CAP3*8 = 62.7 MB) overlays E_a+E_b (76.8 MB): dead after
    // k_compact, before layer-1 bspmm writes E_a (same stream => ordered).
    // Total footprint ~109.5 MB = the R2/R4-proven envelope.
    unsigned long long* staging = (unsigned long long*)E_a;

    const float4* eu4  = (const float4*)eu;
    const float4* ei4s = (const float4*)ei - (size_t)N_USERS * 16;  // float4 units
    const float*  ei_s = ei - (size_t)N_USERS * 64;                 // float units

    hipMemsetAsync(gcnt, 0, (size_t)NSEGF * 4, stream);

    k_part<<<(NNZV + EPB - 1) / EPB, 512, 0, stream>>>(row, col, vals, gcnt, staging);
    k_scanA<<<SCB, 256, 0, stream>>>(gcnt, bsum);
    k_scanB<<<1, 512, 0, stream>>>(bsum);
    k_scanC<<<SCB, 256, 0, stream>>>(gcnt, bsum, seg_ptr);
    k_compact<<<2048, 256, 0, stream>>>(seg_ptr, staging, edges);

    // out = 0.25 * E0[batch]
    k_gather_init<<<(3 * BATCH * 16 + 255) / 256, 256, 0, stream>>>(
        bu, bp, bn, eu4, ei4s, (float4*)out);

    // layer 1: E1 = A * E0 (virtual concat input)
    k_bspmm<<<NBKT, 256, 0, stream>>>(seg_ptr, edges, eu, ei_s, (float4*)E_a);
    k_gather_acc<<<(3 * BATCH * 16 + 255) / 256, 256, 0, stream>>>(
        bu, bp, bn, (const float4*)E_a, (float4*)out);

    // layer 2: E2 = A * E1 (global node ids -> same base twice)
    k_bspmm<<<NBKT, 256, 0, stream>>>(seg_ptr, edges, E_a, E_a, (float4*)E_b);
    k_gather_acc<<<(3 * BATCH * 16 + 255) / 256, 256, 0, stream>>>(
        bu, bp, bn, (const float4*)E_b, (float4*)out);

    // layer 3: E3 = A * E2
    k_bspmm<<<NBKT, 256, 0, stream>>>(seg_ptr, edges, E_b, E_b, (float4*)E_a);
    k_gather_acc<<<(3 * BATCH * 16 + 255) / 256, 256, 0, stream>>>(
        bu, bp, bn, (const float4*)E_a, (float4*)out);
}

// Round 6
// 518.006 us; speedup vs baseline: 8.8314x; 3.7899x over previous
//
#include <hip/hip_runtime.h>

#define N_USERS 100000
#define N_ITEMS 50000
#define N_NODES 150000
#define EMBED   64
#define NNZV    4000000
#define BATCH   4096
// bucket = row >> 9 : 512 rows per bucket, ceil(150000/512) = 293 buckets
#define NBKT    293
// fixed staging capacity per bucket: mean 13,653 + ~21 sigma
#define CAP     16128

// ---------------- Phase A: partition edges into 512-row buckets --------------
// (verbatim from the 515.6us-proven kernel)
__global__ __launch_bounds__(512) void k_parta(
        const int* __restrict__ row, const int* __restrict__ col,
        const float* __restrict__ vals, int* __restrict__ bcnt,
        unsigned long long* __restrict__ staging, int nnz) {
    __shared__ int cnt[512];
    __shared__ int base_s[512];
    int tid = threadIdx.x;
    cnt[tid] = 0;
    __syncthreads();
    int tile0 = blockIdx.x * 16384;
    for (int k = 0; k < 32; k++) {
        int e = tile0 + k * 512 + tid;
        if (e < nnz) atomicAdd(&cnt[row[e] >> 9], 1);
    }
    __syncthreads();
    int c_ = cnt[tid];
    base_s[tid] = c_ ? (tid * CAP + atomicAdd(&bcnt[tid], c_)) : 0;
    __syncthreads();
    cnt[tid] = 0;                                       // reuse as rank counter
    __syncthreads();
    for (int k = 0; k < 32; k++) {
        int e = tile0 + k * 512 + tid;
        if (e < nnz) {
            int r = row[e];
            int b = r >> 9;
            int rank = atomicAdd(&cnt[b], 1);
            unsigned int key = ((unsigned int)(r & 511) << 18) | (unsigned int)col[e];
            unsigned long long rec = (unsigned long long)key
                                   | ((unsigned long long)__float_as_uint(vals[e]) << 32);
            staging[base_s[b] + rank] = rec;
        }
    }
}

// ------- Phase B: bucket scan + per-bucket histogram/scan + local scatter ----
// (verbatim from the 515.6us-proven kernel)
__global__ __launch_bounds__(512) void k_partb(
        const int* __restrict__ bcnt,
        const unsigned long long* __restrict__ staging,
        int* __restrict__ row_ptr,
        unsigned long long* __restrict__ edges) {
    __shared__ int s[512];
    __shared__ int cnt[512];
    __shared__ int cur[512];
    __shared__ int base_sh;
    int b = blockIdx.x;
    int t = threadIdx.x;

    int v = (t < NBKT) ? bcnt[t] : 0;
    s[t] = v;
    __syncthreads();
    for (int off = 1; off < 512; off <<= 1) {
        int u = (t >= off) ? s[t - off] : 0;
        __syncthreads();
        s[t] += u;
        __syncthreads();
    }
    if (t == b) base_sh = s[t] - v;
    if (b == 0 && t == 0) row_ptr[N_NODES] = NNZV;
    __syncthreads();
    int base = base_sh;
    int n    = bcnt[b];
    const unsigned long long* sb = staging + (size_t)b * CAP;

    cnt[t] = 0;
    __syncthreads();
    for (int i = t; i < n; i += 512)
        atomicAdd(&cnt[(unsigned int)sb[i] >> 18], 1);
    __syncthreads();
    int c = cnt[t];
    s[t] = c;
    __syncthreads();
    for (int off = 1; off < 512; off <<= 1) {
        int u = (t >= off) ? s[t - off] : 0;
        __syncthreads();
        s[t] += u;
        __syncthreads();
    }
    int excl = s[t] - c;
    cur[t] = excl;
    int r = (b << 9) + t;
    if (r < N_NODES) row_ptr[r] = base + excl;
    __syncthreads();
    for (int i = t; i < n; i += 512) {
        unsigned long long rec = sb[i];
        unsigned int key = (unsigned int)rec;
        int rank = atomicAdd(&cur[key >> 18], 1);
        edges[base + rank] = (rec & 0xFFFFFFFF00000000ull) | (key & 0x3FFFFu);
    }
}

// ---------------- single-row SpMM helper (R0-proven, used by batch kernel) ---
__device__ __forceinline__ float4 spmm_row(const int* row_ptr,
                                           const unsigned long long* edges,
                                           const float4* __restrict__ eu4,
                                           const float4* __restrict__ ei4s,
                                           int r, int lane) {
    int g = lane >> 4;
    int d = lane & 15;
    int start = row_ptr[r];
    int end   = row_ptr[r + 1];
    float4 acc = make_float4(0.f, 0.f, 0.f, 0.f);
    for (int e0 = start; e0 < end; e0 += 64) {
        int ei = e0 + lane;
        unsigned long long rec = 0ull;
        if (ei < end) rec = __builtin_nontemporal_load(edges + ei);
        int clo = (int)(rec & 0xffffffffull);
        int vhi = (int)(rec >> 32);
        int nleft = end - e0;
        int kmax = (nleft + 3) >> 2;          // uniform across the wave
        #pragma unroll 4
        for (int k = 0; k < kmax; k++) {
            int src = 4 * k + g;
            int cc = __shfl(clo, src);
            float vv = __int_as_float(__shfl(vhi, src));
            const float4* basep = (cc < N_USERS) ? eu4 : ei4s;
            float4 e = basep[cc * 16 + d];
            acc.x += vv * e.x;
            acc.y += vv * e.y;
            acc.z += vv * e.z;
            acc.w += vv * e.w;
        }
    }
    acc.x += __shfl_xor(acc.x, 16);
    acc.y += __shfl_xor(acc.y, 16);
    acc.z += __shfl_xor(acc.z, 16);
    acc.w += __shfl_xor(acc.w, 16);
    acc.x += __shfl_xor(acc.x, 32);
    acc.y += __shfl_xor(acc.y, 32);
    acc.z += __shfl_xor(acc.z, 32);
    acc.w += __shfl_xor(acc.w, 32);
    return acc;
}

// ---------------- 4-row-per-wave SpMM (layers 1 & 2) -------------------------
// R0's spmm was latency-queue-bound (VALU 27%, occ 79%, neither pipe
// saturated) with 4 gathers in flight per wave. This version gives each wave
// FOUR independent rows -> up to 16 float4 gathers in flight (4 rows x
// unroll-4 quarter-wave chains). Wave count 150K -> 37.5K, but resident
// waves/CU unchanged (wave-slot-limited, VGPR ~44 still allows 8/SIMD), so
// per-SIMD outstanding-miss count rises ~2.8x (useful). Per-row kmax_i is
// wave-uniform -> no divergence; rows shorter than the chunk just skip.
__global__ void k_spmm4(const int* __restrict__ row_ptr,
                        const unsigned long long* __restrict__ edges,
                        const float4* __restrict__ eu4,
                        const float4* __restrict__ ei4s,
                        float4* __restrict__ Eout) {
    int lane = threadIdx.x & 63;
    int wv   = threadIdx.x >> 6;
    int rbase = (blockIdx.x * 4 + wv) * 4;       // 4 rows per wave
    if (rbase >= N_NODES) return;
    int g = lane >> 4;
    int d = lane & 15;
    int st[4], en[4], len[4];
    #pragma unroll
    for (int i = 0; i < 4; i++) {
        int r = rbase + i;
        if (r < N_NODES) { st[i] = row_ptr[r]; en[i] = row_ptr[r + 1]; }
        else             { st[i] = 0;          en[i] = 0; }
        len[i] = en[i] - st[i];
    }
    int maxlen = len[0];
    #pragma unroll
    for (int i = 1; i < 4; i++) maxlen = (len[i] > maxlen) ? len[i] : maxlen;

    float4 acc[4];
    #pragma unroll
    for (int i = 0; i < 4; i++) acc[i] = make_float4(0.f, 0.f, 0.f, 0.f);

    for (int off = 0; off < maxlen; off += 64) {
        int clo[4], vhi[4], kmax[4];
        #pragma unroll
        for (int i = 0; i < 4; i++) {
            int ei = st[i] + off + lane;
            unsigned long long rec = 0ull;
            if (ei < en[i]) rec = __builtin_nontemporal_load(edges + ei);
            clo[i] = (int)(rec & 0xffffffffull);
            vhi[i] = (int)(rec >> 32);
            int nleft = len[i] - off;
            if (nleft < 0) nleft = 0; else if (nleft > 64) nleft = 64;
            kmax[i] = (nleft + 3) >> 2;          // wave-uniform per row
        }
        int kmx = (maxlen - off + 3) >> 2; if (kmx > 16) kmx = 16;
        #pragma unroll 4
        for (int k = 0; k < kmx; k++) {
            int src = 4 * k + g;
            #pragma unroll
            for (int i = 0; i < 4; i++) {
                if (k < kmax[i]) {               // wave-uniform branch
                    int cc = __shfl(clo[i], src);
                    float vv = __int_as_float(__shfl(vhi[i], src));
                    const float4* bp = (cc < N_USERS) ? eu4 : ei4s;
                    float4 e = bp[cc * 16 + d];
                    acc[i].x += vv * e.x;
                    acc[i].y += vv * e.y;
                    acc[i].z += vv * e.z;
                    acc[i].w += vv * e.w;
                }
            }
        }
    }
    #pragma unroll
    for (int i = 0; i < 4; i++) {
        acc[i].x += __shfl_xor(acc[i].x, 16);
        acc[i].y += __shfl_xor(acc[i].y, 16);
        acc[i].z += __shfl_xor(acc[i].z, 16);
        acc[i].w += __shfl_xor(acc[i].w, 16);
        acc[i].x += __shfl_xor(acc[i].x, 32);
        acc[i].y += __shfl_xor(acc[i].y, 32);
        acc[i].z += __shfl_xor(acc[i].z, 32);
        acc[i].w += __shfl_xor(acc[i].w, 32);
    }
    if (lane < 16) {
        #pragma unroll
        for (int i = 0; i < 4; i++)
            if (rbase + i < N_NODES) Eout[(rbase + i) * 16 + lane] = acc[i];
    }
}

// --------- layer-3 SpMM restricted to batch rows, fused epilogue -------------
// (verbatim) out[j] += 0.25*E2[r] + 0.25*E3[r]
__global__ void k_spmm_batch(const int* __restrict__ row_ptr,
                             const unsigned long long* __restrict__ edges,
                             const float4* __restrict__ Ein,   // E2
                             const int* __restrict__ bu, const int* __restrict__ bp,
                             const int* __restrict__ bn,
                             float4* __restrict__ out) {
    int lane = threadIdx.x & 63;
    int j = blockIdx.x * 4 + (threadIdx.x >> 6);
    if (j >= 3 * BATCH) return;
    int r;
    if (j < BATCH)          r = bu[j];
    else if (j < 2 * BATCH) r = N_USERS + bp[j - BATCH];
    else                    r = N_USERS + bn[j - 2 * BATCH];
    float4 acc = spmm_row(row_ptr, edges, Ein, Ein, r, lane);
    if (lane < 16) {
        float4 e2 = Ein[r * 16 + lane];
        float4 o  = out[j * 16 + lane];
        o.x += 0.25f * (acc.x + e2.x);
        o.y += 0.25f * (acc.y + e2.y);
        o.z += 0.25f * (acc.z + e2.z);
        o.w += 0.25f * (acc.w + e2.w);
        out[j * 16 + lane] = o;
    }
}

// ---------------- init gather: out = 0.25 * E0[batch] (virtual concat) -------
__global__ void k_gather_init(const int* __restrict__ bu, const int* __restrict__ bp,
                              const int* __restrict__ bn,
                              const float4* __restrict__ eu4,
                              const float4* __restrict__ ei4s,
                              float4* __restrict__ out) {
    int idx = blockIdx.x * blockDim.x + threadIdx.x;
    if (idx >= 3 * BATCH * 16) return;
    int j = idx >> 4;
    int d = idx & 15;
    int node;
    if (j < BATCH)          node = bu[j];
    else if (j < 2 * BATCH) node = N_USERS + bp[j - BATCH];
    else                    node = N_USERS + bn[j - 2 * BATCH];
    const float4* basep = (node < N_USERS) ? eu4 : ei4s;
    float4 v = basep[node * 16 + d];
    v.x *= 0.25f; v.y *= 0.25f; v.z *= 0.25f; v.w *= 0.25f;
    out[idx] = v;
}

// ---------------- accumulate gather: out += 0.25 * E[batch] ------------------
__global__ void k_gather_acc(const int* __restrict__ bu, const int* __restrict__ bp,
                             const int* __restrict__ bn, const float4* __restrict__ E,
                             float4* __restrict__ out) {
    int idx = blockIdx.x * blockDim.x + threadIdx.x;
    if (idx >= 3 * BATCH * 16) return;
    int j = idx >> 4;
    int d = idx & 15;
    int node;
    if (j < BATCH)          node = bu[j];
    else if (j < 2 * BATCH) node = N_USERS + bp[j - BATCH];
    else                    node = N_USERS + bn[j - 2 * BATCH];
    float4 v = E[node * 16 + d];
    float4 o = out[idx];
    o.x += 0.25f * v.x; o.y += 0.25f * v.y; o.z += 0.25f * v.z; o.w += 0.25f * v.w;
    out[idx] = o;
}

extern "C" void kernel_launch(void* const* d_in, const int* in_sizes, int n_in,
                              void* d_out, int out_size, void* d_ws, size_t ws_size,
                              hipStream_t stream) {
    const int*   bu   = (const int*)d_in[0];
    const int*   bp   = (const int*)d_in[1];
    const int*   bn   = (const int*)d_in[2];
    const float* eu   = (const float*)d_in[3];
    const float* ei   = (const float*)d_in[4];
    const int*   row  = (const int*)d_in[5];
    const int*   col  = (const int*)d_in[6];
    const float* vals = (const float*)d_in[7];
    float* out = (float*)d_out;

    char* p = (char*)d_ws;
    auto alloc = [&](size_t nbytes) {
        void* r = (void*)p;
        p += (nbytes + 255) & ~(size_t)255;
        return r;
    };
    float*              E_a     = (float*)alloc((size_t)N_NODES * EMBED * 4);
    float*              E_b     = (float*)alloc((size_t)N_NODES * EMBED * 4);
    unsigned long long* edges   = (unsigned long long*)alloc((size_t)NNZV * 8);
    int*                row_ptr = (int*)alloc((N_NODES + 1) * 4);
    int*                bcnt    = (int*)alloc(512 * 4);
    (void)ws_size; (void)n_in; (void)in_sizes; (void)out_size;

    // staging (NBKT*CAP*8 = 37.8 MB) overlays E_b (38.4 MB): staging is dead
    // after k_partb, before layer-2 spmm writes E_b (same stream => ordered).
    unsigned long long* staging = (unsigned long long*)E_b;

    const float4* eu4  = (const float4*)eu;
    const float4* ei4s = (const float4*)ei - (size_t)N_USERS * 16;  // pre-shifted

    const int nnz = NNZV;
    hipMemsetAsync(bcnt, 0, 512 * sizeof(int), stream);

    k_parta<<<(nnz + 16383) / 16384, 512, 0, stream>>>(row, col, vals, bcnt, staging, nnz);
    k_partb<<<NBKT, 512, 0, stream>>>(bcnt, staging, row_ptr, edges);

    // out = 0.25 * E0[batch]
    k_gather_init<<<(3 * BATCH * 16 + 255) / 256, 256, 0, stream>>>(
        bu, bp, bn, eu4, ei4s, (float4*)out);

    // layer 1: E1 = A * E0 (virtual concat input), 16 rows per 256-thr block
    k_spmm4<<<(N_NODES + 15) / 16, 256, 0, stream>>>(row_ptr, edges, eu4, ei4s,
                                                     (float4*)E_a);
    k_gather_acc<<<(3 * BATCH * 16 + 255) / 256, 256, 0, stream>>>(
        bu, bp, bn, (const float4*)E_a, (float4*)out);

    // layer 2: E2 = A * E1 (global node ids -> same base twice, no shift)
    k_spmm4<<<(N_NODES + 15) / 16, 256, 0, stream>>>(row_ptr, edges,
                                                     (const float4*)E_a,
                                                     (const float4*)E_a,
                                                     (float4*)E_b);

    // layer 3: only batch rows, fused  out += 0.25*E2[batch] + 0.25*E3[batch]
    k_spmm_batch<<<(3 * BATCH + 3) / 4, 256, 0, stream>>>(
        row_ptr, edges, (const float4*)E_b, bu, bp, bn, (float4*)out);
}